// Round 7
// baseline (306.493 us; speedup 1.0000x reference)
//
#include <hip/hip_runtime.h>

#define B_  4
#define C_  64
#define H_  256
#define W_  256
#define HW_ 65536
#define NPIX_ (B_*HW_)        /* 262144 */
#define NELEM_ (B_*C_*HW_)    /* 16777216 */

#define OMS 200     /* bf16 om row stride in LDS (400B: 16B-aligned) */
#define TS  72      /* bf16 sval row stride in LDS (144B: 16B-aligned) */

typedef __attribute__((ext_vector_type(8))) short short8;
typedef __attribute__((ext_vector_type(4))) float floatx4;
typedef __attribute__((ext_vector_type(2))) __fp16 h2f;   // matches cvt_pkrtz return

static __device__ __forceinline__ unsigned short f2bf(float f){
  unsigned u = __float_as_uint(f);
  u += 0x7fff + ((u >> 16) & 1);          // RNE
  return (unsigned short)(u >> 16);
}
static __device__ __forceinline__ float bf2f(unsigned short s){
  return __uint_as_float(((unsigned)s) << 16);
}
static __device__ __forceinline__ unsigned pack2(float a, float b){
  return (unsigned)f2bf(a) | ((unsigned)f2bf(b) << 16);
}

// ---------------- K1: dwconv 3x3 on fp32 x -> t bf16; also emits xB ---------
// Also absorbs: weight bf16 conversion (blocks 0..63) and stats zeroing
// (block 64). Branchless clamped loads; zero-padding folded into weights.
// sched_barrier(0) between stage and consume pins 36 loads in flight.
__global__ __launch_bounds__(256) void k_dwconv(
    const float* __restrict__ x,
    const float* __restrict__ dwW,
    const float* __restrict__ pw,
    const float* __restrict__ w2,
    unsigned short* __restrict__ wB,
    float* __restrict__ stats0,          // 4096 floats (gsum+gsq slots)
    unsigned short* __restrict__ xB,
    unsigned short* __restrict__ t)
{
  int tid = threadIdx.x;
  if (blockIdx.x < 64){
    int i = blockIdx.x*256 + tid;
    wB[i] = f2bf(i < 12288 ? pw[i] : w2[i - 12288]);
  } else if (blockIdx.x == 64){
#pragma unroll
    for (int k = 0; k < 16; ++k) stats0[k*256 + tid] = 0.f;
  }

  int bid = ((blockIdx.x & 7) << 9) + (blockIdx.x >> 3);   // XCD-contiguous
  int b    = bid >> 10;
  int tile = bid & 1023;
  int h    = tile >> 2;
  int w0   = (tile & 3) << 6;
  int p  = tid & 63;
  int cg = tid >> 6;
  int wg = w0 + p;

  // clamped row bases (h block-uniform -> scalar), validity as weight scale
  int rm = (h > 0   ? h-1 : 0) << 8;
  int r0 = h << 8;
  int rp = (h < 255 ? h+1 : 255) << 8;
  float vm = (h > 0)   ? 1.f : 0.f;
  float vp = (h < 255) ? 1.f : 0.f;
  // clamped col offsets (per-lane, once)
  int wl = wg > 0   ? wg-1 : 0;
  int wr = wg < 255 ? wg+1 : 255;
  bool ml = (wg > 0);
  bool mr = (wg < 255);

  // 9 tap offsets (elements) within a plane, shared across channels
  int o0 = rm + wl, o1 = rm + wg, o2 = rm + wr;
  int o3 = r0 + wl, o4 = r0 + wg, o5 = r0 + wr;
  int o6 = rp + wl, o7 = rp + wg, o8 = rp + wr;

  const float* plane0 = x + ((size_t)(b*C_ + cg*16) << 16);

  unsigned pk[8];
#pragma unroll
  for (int ib = 0; ib < 4; ++ib){       // 4 batches of 4 channels
    float v[4][9];
    // ---- stage: 36 independent loads ----
#pragma unroll
    for (int j = 0; j < 4; ++j){
      const float* pl = plane0 + ((size_t)(ib*4 + j) << 16);
      v[j][0] = pl[o0]; v[j][1] = pl[o1]; v[j][2] = pl[o2];
      v[j][3] = pl[o3]; v[j][4] = pl[o4]; v[j][5] = pl[o5];
      v[j][6] = pl[o6]; v[j][7] = pl[o7]; v[j][8] = pl[o8];
    }
    __builtin_amdgcn_sched_barrier(0);   // loads may not sink past this
    // ---- consume ----
#pragma unroll
    for (int j = 0; j < 4; ++j){
      int i = ib*4 + j;
      int c = cg*16 + i;
      const float* wp = dwW + c*9;       // wave-uniform -> scalar loads
      float w00 = wp[0]*vm, w01 = wp[1]*vm, w02 = wp[2]*vm;
      float w20 = wp[6]*vp, w21 = wp[7]*vp, w22 = wp[8]*vp;
      float l0 = ml ? v[j][0] : 0.f, g0 = mr ? v[j][2] : 0.f;
      float l1 = ml ? v[j][3] : 0.f, g1 = mr ? v[j][5] : 0.f;
      float l2 = ml ? v[j][6] : 0.f, g2 = mr ? v[j][8] : 0.f;
      float acc = w00*l0 + w01*v[j][1] + w02*g0
                + wp[3]*l1 + wp[4]*v[j][4] + wp[5]*g1
                + w20*l2 + w21*v[j][7] + w22*g2;
      xB[((size_t)(b*C_ + c) << 16) + r0 + wg] = f2bf(v[j][4]);
      unsigned short bv = f2bf(acc);
      if (i & 1) pk[i>>1] |= ((unsigned)bv << 16);
      else       pk[i>>1]  = (unsigned)bv;
    }
  }
  size_t rowbase = ((size_t)bid*64 + p)*64 + cg*16;
  uint4 u0; u0.x = pk[0]; u0.y = pk[1]; u0.z = pk[2]; u0.w = pk[3];
  uint4 u1; u1.x = pk[4]; u1.y = pk[5]; u1.z = pk[6]; u1.w = pk[7];
  *(uint4*)(t + rowbase)     = u0;
  *(uint4*)(t + rowbase + 8) = u1;
}

// ---------------- K2: fused GEMM1 -> sample -> GEMM2 (+BN partials) ---------
// Phase B is forced into stage(addr+weights) -> issue 32 loads ->
// sched_barrier -> consume. Weights packed fp16x2 (v_cvt_pkrtz) so the
// staged state fits: 16x2 packed weights + 32 pu + addr temps ~= 100 VGPR.
// launch_bounds(256,4) gives the 128-VGPR budget (16 waves/CU, same
// occupancy as measured at (256,5): ~15 waves/CU).
__global__ __launch_bounds__(256, 4) void k_fuse(
    const unsigned short* __restrict__ xB,
    const unsigned short* __restrict__ t,
    const unsigned short* __restrict__ pwB,
    const unsigned short* __restrict__ w2B,
    unsigned short* __restrict__ outB,
    float* __restrict__ gsumS,
    float* __restrict__ gsqS)
{
  __shared__ __align__(16) char lds[25600];
  unsigned short* OM = (unsigned short*)lds;        // 64 x OMS bf16 (25600 B)
  unsigned short* T  = (unsigned short*)lds;        // 64 x TS bf16 (overlays OM)
  float* red1 = (float*)(lds + 9216);               // 4 x 64 (overlays dead OM tail)
  float* red2 = (float*)(lds + 10240);              // 4 x 64

  int tid = threadIdx.x;
  int bid = ((blockIdx.x & 7) << 9) + (blockIdx.x >> 3);   // XCD-contiguous
  int wv = tid >> 6, lane = tid & 63;
  int mrow = lane & 15, q = lane >> 4;
  int px0 = bid*64;
  int pxw = px0 + wv*16;        // wave's pixel base (16 px per wave)

  // ---- phase A: GEMM1  om[px][ch] = sum_c t[px][c]*pw[ch][c] ----
  short8 bfrag[2];
#pragma unroll
  for (int kb = 0; kb < 2; ++kb)
    bfrag[kb] = *(const short8*)(t + (size_t)(pxw + mrow)*64 + kb*32 + q*8);

  floatx4 acc[12];
#pragma unroll
  for (int mt = 0; mt < 12; ++mt) acc[mt] = (floatx4){0.f,0.f,0.f,0.f};
#pragma unroll
  for (int kb = 0; kb < 2; ++kb)
#pragma unroll
    for (int mt = 0; mt < 12; ++mt){
      short8 af = *(const short8*)(pwB + (mt*16 + mrow)*64 + kb*32 + q*8);
      acc[mt] = __builtin_amdgcn_mfma_f32_16x16x32_bf16(af, bfrag[kb], acc[mt], 0, 0, 0);
    }

  {
    int omrow = (wv*16 + mrow)*OMS;
#pragma unroll
    for (int mt = 0; mt < 12; ++mt){
      uint2 u; u.x = pack2(acc[mt][0], acc[mt][1]); u.y = pack2(acc[mt][2], acc[mt][3]);
      *(uint2*)(OM + omrow + mt*16 + q*4) = u;
    }
  }
  __syncthreads();

  // ---- phase B: deformable bilinear sampling from bf16 x ----
  unsigned pk[8];
  {
    int pl = tid & 63;          // block-local pixel   (quad = 4 adjacent px)
    int cg = tid >> 6;          // channel group       (wave-uniform)
    int px = px0 + pl;
    int b = px >> 16;
    int p = px & (HW_-1);
    int h = p >> 8, w = p & (W_-1);

    const char* xbyte = (const char*)(xB + ((size_t)(b*C_ + cg*16) << 16));
    float hf = (float)h, wf = (float)w;

    // read all OM data for this (pixel, channel-group)
    const uint4* ob = (const uint4*)(OM + pl*OMS + cg*32);
    uint4 oA = ob[0], oB = ob[1], oC = ob[2], oD = ob[3];
    const uint4* mb = (const uint4*)(OM + pl*OMS + 128 + cg*16);
    uint4 mA = mb[0], mB = mb[1];
    unsigned pr[16] = {oA.x,oA.y,oA.z,oA.w, oB.x,oB.y,oB.z,oB.w,
                       oC.x,oC.y,oC.z,oC.w, oD.x,oD.y,oD.z,oD.w};
    unsigned md[8]  = {mA.x,mA.y,mA.z,mA.w, mB.x,mB.y,mB.z,mB.w};

    h2f wrv[16];                 // packed (rw0, rw1)
    h2f wcv[16];                 // packed (cwA, cwB)
    unsigned ad0[16], ad1[16];

    // ---- stage 1: weights + addresses, all 16 channels (VALU only) ----
#pragma unroll
    for (int i = 0; i < 16; ++i){
      unsigned pair = pr[i];
      float oy = __uint_as_float(pair << 16);
      float ox = __uint_as_float(pair & 0xffff0000u);
      float mm = __uint_as_float((i & 1) ? (md[i>>1] & 0xffff0000u)
                                         : (md[i>>1] << 16));
      float mod = 2.f * __builtin_amdgcn_rcpf(1.f + __expf(-mm));
      oy = fminf(fmaxf(oy, -64.f), 64.f);
      ox = fminf(fmaxf(ox, -64.f), 64.f);
      float sy = hf + oy, sx = wf + ox;
      float y0f = floorf(sy), x0f = floorf(sx);
      float wy = sy - y0f, wxr = sx - x0f;
      int y0 = (int)y0f, x0 = (int)x0f;
      int yc0 = min(max(y0,     0), 255);
      int yc1 = min(max(y0 + 1, 0), 255);    // clamp AFTER increment
      int xc  = min(max(x0, 0), 254);        // pair start (always in-plane)
      bool y0v = ((unsigned)y0       < 256u);
      bool y1v = ((unsigned)(y0 + 1) < 256u);
      bool x0v = ((unsigned)x0       < 256u);
      bool x1v = ((unsigned)(x0 + 1) < 256u);
      bool x0lo = (x0 == xc);
      float r0 = y0v ? (1.f - wy) * mod : 0.f;
      float r1 = y1v ? wy * mod : 0.f;
      float c0w = x0v ? (1.f - wxr) : 0.f;
      float c1w = x1v ? wxr : 0.f;
      float cA = x0lo ? c0w : c1w;           // weight on value at xc
      float cB = x0lo ? c1w : c0w;           // weight on value at xc+1
      wrv[i] = __builtin_amdgcn_cvt_pkrtz(r0, r1);
      wcv[i] = __builtin_amdgcn_cvt_pkrtz(cA, cB);
      unsigned cb = ((unsigned)i) << 17;     // channel byte offset in group
      ad0[i] = cb + ((unsigned)yc0 << 9) + ((unsigned)xc << 1);
      ad1[i] = cb + ((unsigned)yc1 << 9) + ((unsigned)xc << 1);
    }

    // ---- stage 2: issue ALL 32 gathers ----
    unsigned pu0[16], pu1[16];
#pragma unroll
    for (int i = 0; i < 16; ++i){
      __builtin_memcpy(&pu0[i], xbyte + ad0[i], 4);   // (y0 row, x: xc..xc+1)
      __builtin_memcpy(&pu1[i], xbyte + ad1[i], 4);   // (y0+1 row, same)
    }
    __builtin_amdgcn_sched_barrier(0);   // loads may not sink below here

    // ---- stage 3: consume ----
#pragma unroll
    for (int i = 0; i < 16; ++i){
      float lo0 = __uint_as_float(pu0[i] << 16);
      float hi0 = __uint_as_float(pu0[i] & 0xffff0000u);
      float lo1 = __uint_as_float(pu1[i] << 16);
      float hi1 = __uint_as_float(pu1[i] & 0xffff0000u);
      float cA = (float)wcv[i].x, cB = (float)wcv[i].y;
      float r0 = (float)wrv[i].x, r1 = (float)wrv[i].y;
      float s0 = cA*lo0 + cB*hi0;
      float s1 = cA*lo1 + cB*hi1;
      float sres = r0*s0 + r1*s1;
      unsigned short bv = f2bf(sres);
      if (i & 1) pk[i>>1] |= ((unsigned)bv << 16);
      else       pk[i>>1]  = (unsigned)bv;
    }
  }
  __syncthreads();              // all OM reads done before T overlays it

  {
    int pl = tid & 63, cg = tid >> 6;
    uint4 u0; u0.x = pk[0]; u0.y = pk[1]; u0.z = pk[2]; u0.w = pk[3];
    uint4 u1; u1.x = pk[4]; u1.y = pk[5]; u1.z = pk[6]; u1.w = pk[7];
    *(uint4*)(T + pl*TS + cg*16)     = u0;
    *(uint4*)(T + pl*TS + cg*16 + 8) = u1;
  }
  __syncthreads();

  // ---- phase C: GEMM2  out[px][och] = sum_c sval[px][c]*w2[och][c] ----
  short8 a2[2];
#pragma unroll
  for (int kb = 0; kb < 2; ++kb)
    a2[kb] = *(const short8*)(T + (wv*16 + mrow)*TS + kb*32 + q*8);

  floatx4 acc2[4];
#pragma unroll
  for (int nt = 0; nt < 4; ++nt) acc2[nt] = (floatx4){0.f,0.f,0.f,0.f};
#pragma unroll
  for (int kb = 0; kb < 2; ++kb)
#pragma unroll
    for (int nt = 0; nt < 4; ++nt){
      short8 bf = *(const short8*)(w2B + (nt*16 + mrow)*64 + kb*32 + q*8);
      acc2[nt] = __builtin_amdgcn_mfma_f32_16x16x32_bf16(a2[kb], bf, acc2[nt], 0, 0, 0);
    }

  int b   = pxw >> 16;
  int hw0 = pxw & (HW_-1);
#pragma unroll
  for (int nt = 0; nt < 4; ++nt){
    int och = nt*16 + mrow;
    float a0 = acc2[nt][0], a1 = acc2[nt][1], a2v = acc2[nt][2], a3 = acc2[nt][3];
    uint2 u; u.x = pack2(a0, a1); u.y = pack2(a2v, a3);
    *(uint2*)(outB + ((size_t)(b*C_ + och) << 16) + hw0 + q*4) = u;
    float s1 = a0 + a1 + a2v + a3;
    float s2 = a0*a0 + a1*a1 + a2v*a2v + a3*a3;
    s1 += __shfl_xor(s1, 16, 64);  s2 += __shfl_xor(s2, 16, 64);
    s1 += __shfl_xor(s1, 32, 64);  s2 += __shfl_xor(s2, 32, 64);
    if (q == 0){ red1[wv*64 + och] = s1; red2[wv*64 + och] = s2; }
  }
  __syncthreads();
  if (tid < 64){
    float t1 = red1[tid] + red1[64+tid] + red1[128+tid] + red1[192+tid];
    float t2 = red2[tid] + red2[64+tid] + red2[128+tid] + red2[192+tid];
    int slot = blockIdx.x & 31;
    atomicAdd(&gsumS[slot*64 + tid], t1);
    atomicAdd(&gsqS[slot*64 + tid], t2);
  }
}

// ---------------- K5: BN finalize (redundant per block) + apply + GELU ------
__global__ __launch_bounds__(256) void k_bn_gelu(
    const uint4* __restrict__ outB4,   // 8 bf16
    const float* __restrict__ gsumS,
    const float* __restrict__ gsqS,
    const float* __restrict__ gamma,
    const float* __restrict__ beta,
    float4* __restrict__ y4)
{
  int i = blockIdx.x*256 + threadIdx.x;           // over NELEM_/8
  int och = (i >> 13) & 63;                       // block-uniform
  float s1 = 0.f, s2 = 0.f;
#pragma unroll
  for (int s = 0; s < 32; ++s){ s1 += gsumS[s*64 + och]; s2 += gsqS[s*64 + och]; }
  float mean = s1 * (1.f/(float)NPIX_);
  float var  = s2 * (1.f/(float)NPIX_) - mean*mean;   // biased, matches jnp.var
  float sc = gamma[och] * rsqrtf(var + 1e-5f);
  float sh = beta[och] - mean*sc;

  uint4 u = outB4[i];
  float e[8];
  e[0] = bf2f((unsigned short)(u.x & 0xffffu)); e[1] = bf2f((unsigned short)(u.x >> 16));
  e[2] = bf2f((unsigned short)(u.y & 0xffffu)); e[3] = bf2f((unsigned short)(u.y >> 16));
  e[4] = bf2f((unsigned short)(u.z & 0xffffu)); e[5] = bf2f((unsigned short)(u.z >> 16));
  e[6] = bf2f((unsigned short)(u.w & 0xffffu)); e[7] = bf2f((unsigned short)(u.w >> 16));
  float4 o0, o1;
  float a;
  a = e[0]*sc + sh; o0.x = 0.5f*a*(1.f + erff(a*0.70710678118654752f));
  a = e[1]*sc + sh; o0.y = 0.5f*a*(1.f + erff(a*0.70710678118654752f));
  a = e[2]*sc + sh; o0.z = 0.5f*a*(1.f + erff(a*0.70710678118654752f));
  a = e[3]*sc + sh; o0.w = 0.5f*a*(1.f + erff(a*0.70710678118654752f));
  a = e[4]*sc + sh; o1.x = 0.5f*a*(1.f + erff(a*0.70710678118654752f));
  a = e[5]*sc + sh; o1.y = 0.5f*a*(1.f + erff(a*0.70710678118654752f));
  a = e[6]*sc + sh; o1.z = 0.5f*a*(1.f + erff(a*0.70710678118654752f));
  a = e[7]*sc + sh; o1.w = 0.5f*a*(1.f + erff(a*0.70710678118654752f));
  y4[2*i]   = o0;
  y4[2*i+1] = o1;
}

extern "C" void kernel_launch(void* const* d_in, const int* in_sizes, int n_in,
                              void* d_out, int out_size, void* d_ws, size_t ws_size,
                              hipStream_t stream)
{
  (void)in_sizes; (void)n_in; (void)out_size; (void)ws_size;
  const float* x     = (const float*)d_in[0];
  const float* dw    = (const float*)d_in[1];
  const float* pw    = (const float*)d_in[2];
  const float* w2    = (const float*)d_in[3];
  /* d_in[4] = bias: cancels exactly in BN (mean-subtracted), unused */
  const float* gamma = (const float*)d_in[5];
  const float* beta  = (const float*)d_in[6];

  // ws layout:
  //   [0,          33554432)  xB    bf16 x
  //   [33554432,   67108864)  t     bf16 dwconv out [px][c]
  //   [67108864,  100663296)  outB  bf16 conv2 out, och-major
  //   [100663296, 100680192)  stats (gsumS 8K, gsqS 8K)
  //   [100680192, 100712960)  wB    bf16 weights (pw 24K, w2 8K)
  char* ws = (char*)d_ws;
  unsigned short* xB    = (unsigned short*)ws;
  unsigned short* t     = (unsigned short*)(ws + 33554432);
  unsigned short* outB  = (unsigned short*)(ws + 67108864);
  float*          stats = (float*)(ws + 100663296);
  float* gsumS = stats;                 // 32 slots x 64
  float* gsqS  = stats + 2048;
  unsigned short* wB  = (unsigned short*)(ws + 100680192);
  unsigned short* pwB = wB;
  unsigned short* w2B = wB + 12288;

  k_dwconv  <<<NPIX_/64, 256, 0, stream>>>(x, dw, pw, w2, wB, stats, xB, t);
  k_fuse    <<<NPIX_/64, 256, 0, stream>>>(xB, t, pwB, w2B, outB, gsumS, gsqS);
  k_bn_gelu <<<NELEM_/8/256, 256, 0, stream>>>((const uint4*)outB, gsumS, gsqS,
                                               gamma, beta, (float4*)d_out);
}

// Round 8
// 298.325 us; speedup vs baseline: 1.0274x; 1.0274x over previous
//
#include <hip/hip_runtime.h>

#define B_  4
#define C_  64
#define H_  256
#define W_  256
#define HW_ 65536
#define NPIX_ (B_*HW_)        /* 262144 */
#define NELEM_ (B_*C_*HW_)    /* 16777216 */

#define OMS 200     /* bf16 om row stride in LDS (400B: 16B-aligned) */
#define TS  72      /* bf16 sval row stride in LDS (144B: 16B-aligned) */

typedef __attribute__((ext_vector_type(8))) short short8;
typedef __attribute__((ext_vector_type(4))) float floatx4;
typedef __attribute__((ext_vector_type(2))) __fp16 h2f;   // matches cvt_pkrtz return

static __device__ __forceinline__ unsigned short f2bf(float f){
  unsigned u = __float_as_uint(f);
  u += 0x7fff + ((u >> 16) & 1);          // RNE
  return (unsigned short)(u >> 16);
}
static __device__ __forceinline__ float bf2f(unsigned short s){
  return __uint_as_float(((unsigned)s) << 16);
}
static __device__ __forceinline__ unsigned pack2(float a, float b){
  return (unsigned)f2bf(a) | ((unsigned)f2bf(b) << 16);
}

// ---------------- K1: dwconv 3x3 on fp32 x -> t bf16; also emits xB ---------
// Absorbs weight conversion (blocks 0..63) + stats zeroing (block 64).
// Per channel-row the 3 overlapping taps are ONE 12B dwordx3 load; the
// clamp/zero-pad logic is a select network on d = wg - st (0: left edge,
// 2: right edge, 1: interior). 48 VMEM inst/thread (was 144), ~2.7x fewer
// cache-line probes per wave-instruction.
__global__ __launch_bounds__(256) void k_dwconv(
    const float* __restrict__ x,
    const float* __restrict__ dwW,
    const float* __restrict__ pw,
    const float* __restrict__ w2,
    unsigned short* __restrict__ wB,
    float* __restrict__ stats0,          // 4096 floats (gsum+gsq slots)
    unsigned short* __restrict__ xB,
    unsigned short* __restrict__ t)
{
  int tid = threadIdx.x;
  if (blockIdx.x < 64){
    int i = blockIdx.x*256 + tid;
    wB[i] = f2bf(i < 12288 ? pw[i] : w2[i - 12288]);
  } else if (blockIdx.x == 64){
#pragma unroll
    for (int k = 0; k < 16; ++k) stats0[k*256 + tid] = 0.f;
  }

  int bid = ((blockIdx.x & 7) << 9) + (blockIdx.x >> 3);   // XCD-contiguous
  int b    = bid >> 10;
  int tile = bid & 1023;
  int h    = tile >> 2;
  int w0   = (tile & 3) << 6;
  int p  = tid & 63;
  int cg = tid >> 6;
  int wg = w0 + p;

  // clamped row bases (h block-uniform -> scalar); row validity as weight scale
  int rm = (h > 0   ? h-1 : 0) << 8;
  int r0 = h << 8;
  int rp = (h < 255 ? h+1 : 255) << 8;
  float vm = (h > 0)   ? 1.f : 0.f;
  float vp = (h < 255) ? 1.f : 0.f;

  // 12B window start column and lane-position within it
  int st = min(max(wg - 1, 0), 253);
  int d  = wg - st;                      // 0: wg==0, 2: wg==255, else 1
  bool d0 = (d == 0), d2 = (d == 2);

  // byte offsets of the 3 row windows (shared across channels)
  int om = (rm + st) << 2;
  int oc = (r0 + st) << 2;
  int op = (rp + st) << 2;

  const char* plane0 = (const char*)(x + ((size_t)(b*C_ + cg*16) << 16));

  unsigned pk[8];
#pragma unroll
  for (int ib = 0; ib < 4; ++ib){       // 4 batches of 4 channels
    float3 v[4][3];
    // ---- stage: 12 independent dwordx3 loads ----
#pragma unroll
    for (int j = 0; j < 4; ++j){
      const char* pl = plane0 + (((size_t)(ib*4 + j)) << 18);
      __builtin_memcpy(&v[j][0], pl + om, 12);
      __builtin_memcpy(&v[j][1], pl + oc, 12);
      __builtin_memcpy(&v[j][2], pl + op, 12);
    }
    __builtin_amdgcn_sched_barrier(0);   // loads may not sink past this
    // ---- consume ----
#pragma unroll
    for (int j = 0; j < 4; ++j){
      int i = ib*4 + j;
      int c = cg*16 + i;
      const float* wp = dwW + c*9;       // wave-uniform -> scalar loads
      float acc = 0.f, ctr = 0.f;
#pragma unroll
      for (int r = 0; r < 3; ++r){
        float3 f = v[j][r];
        float xl = d0 ? 0.f : (d2 ? f.y : f.x);
        float xc = d0 ? f.x : (d2 ? f.z : f.y);
        float xr = d2 ? 0.f : (d0 ? f.y : f.z);
        float rowscale = (r == 0) ? vm : (r == 2 ? vp : 1.f);
        acc += rowscale * (wp[r*3+0]*xl + wp[r*3+1]*xc + wp[r*3+2]*xr);
        if (r == 1) ctr = xc;
      }
      xB[((size_t)(b*C_ + c) << 16) + r0 + wg] = f2bf(ctr);
      unsigned short bv = f2bf(acc);
      if (i & 1) pk[i>>1] |= ((unsigned)bv << 16);
      else       pk[i>>1]  = (unsigned)bv;
    }
  }
  size_t rowbase = ((size_t)bid*64 + p)*64 + cg*16;
  uint4 u0; u0.x = pk[0]; u0.y = pk[1]; u0.z = pk[2]; u0.w = pk[3];
  uint4 u1; u1.x = pk[4]; u1.y = pk[5]; u1.z = pk[6]; u1.w = pk[7];
  *(uint4*)(t + rowbase)     = u0;
  *(uint4*)(t + rowbase + 8) = u1;
}

// ---------------- K2: fused GEMM1 -> sample -> GEMM2 (+BN partials) ---------
// (unchanged from round 7 passing version)
__global__ __launch_bounds__(256, 4) void k_fuse(
    const unsigned short* __restrict__ xB,
    const unsigned short* __restrict__ t,
    const unsigned short* __restrict__ pwB,
    const unsigned short* __restrict__ w2B,
    unsigned short* __restrict__ outB,
    float* __restrict__ gsumS,
    float* __restrict__ gsqS)
{
  __shared__ __align__(16) char lds[25600];
  unsigned short* OM = (unsigned short*)lds;        // 64 x OMS bf16 (25600 B)
  unsigned short* T  = (unsigned short*)lds;        // 64 x TS bf16 (overlays OM)
  float* red1 = (float*)(lds + 9216);               // 4 x 64 (overlays dead OM tail)
  float* red2 = (float*)(lds + 10240);              // 4 x 64

  int tid = threadIdx.x;
  int bid = ((blockIdx.x & 7) << 9) + (blockIdx.x >> 3);   // XCD-contiguous
  int wv = tid >> 6, lane = tid & 63;
  int mrow = lane & 15, q = lane >> 4;
  int px0 = bid*64;
  int pxw = px0 + wv*16;        // wave's pixel base (16 px per wave)

  // ---- phase A: GEMM1  om[px][ch] = sum_c t[px][c]*pw[ch][c] ----
  short8 bfrag[2];
#pragma unroll
  for (int kb = 0; kb < 2; ++kb)
    bfrag[kb] = *(const short8*)(t + (size_t)(pxw + mrow)*64 + kb*32 + q*8);

  floatx4 acc[12];
#pragma unroll
  for (int mt = 0; mt < 12; ++mt) acc[mt] = (floatx4){0.f,0.f,0.f,0.f};
#pragma unroll
  for (int kb = 0; kb < 2; ++kb)
#pragma unroll
    for (int mt = 0; mt < 12; ++mt){
      short8 af = *(const short8*)(pwB + (mt*16 + mrow)*64 + kb*32 + q*8);
      acc[mt] = __builtin_amdgcn_mfma_f32_16x16x32_bf16(af, bfrag[kb], acc[mt], 0, 0, 0);
    }

  {
    int omrow = (wv*16 + mrow)*OMS;
#pragma unroll
    for (int mt = 0; mt < 12; ++mt){
      uint2 u; u.x = pack2(acc[mt][0], acc[mt][1]); u.y = pack2(acc[mt][2], acc[mt][3]);
      *(uint2*)(OM + omrow + mt*16 + q*4) = u;
    }
  }
  __syncthreads();

  // ---- phase B: deformable bilinear sampling from bf16 x ----
  unsigned pk[8];
  {
    int pl = tid & 63;          // block-local pixel   (quad = 4 adjacent px)
    int cg = tid >> 6;          // channel group       (wave-uniform)
    int px = px0 + pl;
    int b = px >> 16;
    int p = px & (HW_-1);
    int h = p >> 8, w = p & (W_-1);

    const char* xbyte = (const char*)(xB + ((size_t)(b*C_ + cg*16) << 16));
    float hf = (float)h, wf = (float)w;

    // read all OM data for this (pixel, channel-group)
    const uint4* ob = (const uint4*)(OM + pl*OMS + cg*32);
    uint4 oA = ob[0], oB = ob[1], oC = ob[2], oD = ob[3];
    const uint4* mb = (const uint4*)(OM + pl*OMS + 128 + cg*16);
    uint4 mA = mb[0], mB = mb[1];
    unsigned pr[16] = {oA.x,oA.y,oA.z,oA.w, oB.x,oB.y,oB.z,oB.w,
                       oC.x,oC.y,oC.z,oC.w, oD.x,oD.y,oD.z,oD.w};
    unsigned md[8]  = {mA.x,mA.y,mA.z,mA.w, mB.x,mB.y,mB.z,mB.w};

    h2f wrv[16];                 // packed (rw0, rw1)
    h2f wcv[16];                 // packed (cwA, cwB)
    unsigned ad0[16], ad1[16];

    // ---- stage 1: weights + addresses, all 16 channels (VALU only) ----
#pragma unroll
    for (int i = 0; i < 16; ++i){
      unsigned pair = pr[i];
      float oy = __uint_as_float(pair << 16);
      float ox = __uint_as_float(pair & 0xffff0000u);
      float mm = __uint_as_float((i & 1) ? (md[i>>1] & 0xffff0000u)
                                         : (md[i>>1] << 16));
      float mod = 2.f * __builtin_amdgcn_rcpf(1.f + __expf(-mm));
      oy = fminf(fmaxf(oy, -64.f), 64.f);
      ox = fminf(fmaxf(ox, -64.f), 64.f);
      float sy = hf + oy, sx = wf + ox;
      float y0f = floorf(sy), x0f = floorf(sx);
      float wy = sy - y0f, wxr = sx - x0f;
      int y0 = (int)y0f, x0 = (int)x0f;
      int yc0 = min(max(y0,     0), 255);
      int yc1 = min(max(y0 + 1, 0), 255);    // clamp AFTER increment
      int xc  = min(max(x0, 0), 254);        // pair start (always in-plane)
      bool y0v = ((unsigned)y0       < 256u);
      bool y1v = ((unsigned)(y0 + 1) < 256u);
      bool x0v = ((unsigned)x0       < 256u);
      bool x1v = ((unsigned)(x0 + 1) < 256u);
      bool x0lo = (x0 == xc);
      float r0 = y0v ? (1.f - wy) * mod : 0.f;
      float r1 = y1v ? wy * mod : 0.f;
      float c0w = x0v ? (1.f - wxr) : 0.f;
      float c1w = x1v ? wxr : 0.f;
      float cA = x0lo ? c0w : c1w;           // weight on value at xc
      float cB = x0lo ? c1w : c0w;           // weight on value at xc+1
      wrv[i] = __builtin_amdgcn_cvt_pkrtz(r0, r1);
      wcv[i] = __builtin_amdgcn_cvt_pkrtz(cA, cB);
      unsigned cb = ((unsigned)i) << 17;     // channel byte offset in group
      ad0[i] = cb + ((unsigned)yc0 << 9) + ((unsigned)xc << 1);
      ad1[i] = cb + ((unsigned)yc1 << 9) + ((unsigned)xc << 1);
    }

    // ---- stage 2: issue ALL 32 gathers ----
    unsigned pu0[16], pu1[16];
#pragma unroll
    for (int i = 0; i < 16; ++i){
      __builtin_memcpy(&pu0[i], xbyte + ad0[i], 4);   // (y0 row, x: xc..xc+1)
      __builtin_memcpy(&pu1[i], xbyte + ad1[i], 4);   // (y0+1 row, same)
    }
    __builtin_amdgcn_sched_barrier(0);   // loads may not sink below here

    // ---- stage 3: consume ----
#pragma unroll
    for (int i = 0; i < 16; ++i){
      float lo0 = __uint_as_float(pu0[i] << 16);
      float hi0 = __uint_as_float(pu0[i] & 0xffff0000u);
      float lo1 = __uint_as_float(pu1[i] << 16);
      float hi1 = __uint_as_float(pu1[i] & 0xffff0000u);
      float cA = (float)wcv[i].x, cB = (float)wcv[i].y;
      float r0 = (float)wrv[i].x, r1 = (float)wrv[i].y;
      float s0 = cA*lo0 + cB*hi0;
      float s1 = cA*lo1 + cB*hi1;
      float sres = r0*s0 + r1*s1;
      unsigned short bv = f2bf(sres);
      if (i & 1) pk[i>>1] |= ((unsigned)bv << 16);
      else       pk[i>>1]  = (unsigned)bv;
    }
  }
  __syncthreads();              // all OM reads done before T overlays it

  {
    int pl = tid & 63, cg = tid >> 6;
    uint4 u0; u0.x = pk[0]; u0.y = pk[1]; u0.z = pk[2]; u0.w = pk[3];
    uint4 u1; u1.x = pk[4]; u1.y = pk[5]; u1.z = pk[6]; u1.w = pk[7];
    *(uint4*)(T + pl*TS + cg*16)     = u0;
    *(uint4*)(T + pl*TS + cg*16 + 8) = u1;
  }
  __syncthreads();

  // ---- phase C: GEMM2  out[px][och] = sum_c sval[px][c]*w2[och][c] ----
  short8 a2[2];
#pragma unroll
  for (int kb = 0; kb < 2; ++kb)
    a2[kb] = *(const short8*)(T + (wv*16 + mrow)*TS + kb*32 + q*8);

  floatx4 acc2[4];
#pragma unroll
  for (int nt = 0; nt < 4; ++nt) acc2[nt] = (floatx4){0.f,0.f,0.f,0.f};
#pragma unroll
  for (int kb = 0; kb < 2; ++kb)
#pragma unroll
    for (int nt = 0; nt < 4; ++nt){
      short8 bf = *(const short8*)(w2B + (nt*16 + mrow)*64 + kb*32 + q*8);
      acc2[nt] = __builtin_amdgcn_mfma_f32_16x16x32_bf16(a2[kb], bf, acc2[nt], 0, 0, 0);
    }

  int b   = pxw >> 16;
  int hw0 = pxw & (HW_-1);
#pragma unroll
  for (int nt = 0; nt < 4; ++nt){
    int och = nt*16 + mrow;
    float a0 = acc2[nt][0], a1 = acc2[nt][1], a2v = acc2[nt][2], a3 = acc2[nt][3];
    uint2 u; u.x = pack2(a0, a1); u.y = pack2(a2v, a3);
    *(uint2*)(outB + ((size_t)(b*C_ + och) << 16) + hw0 + q*4) = u;
    float s1 = a0 + a1 + a2v + a3;
    float s2 = a0*a0 + a1*a1 + a2v*a2v + a3*a3;
    s1 += __shfl_xor(s1, 16, 64);  s2 += __shfl_xor(s2, 16, 64);
    s1 += __shfl_xor(s1, 32, 64);  s2 += __shfl_xor(s2, 32, 64);
    if (q == 0){ red1[wv*64 + och] = s1; red2[wv*64 + och] = s2; }
  }
  __syncthreads();
  if (tid < 64){
    float t1 = red1[tid] + red1[64+tid] + red1[128+tid] + red1[192+tid];
    float t2 = red2[tid] + red2[64+tid] + red2[128+tid] + red2[192+tid];
    int slot = blockIdx.x & 31;
    atomicAdd(&gsumS[slot*64 + tid], t1);
    atomicAdd(&gsqS[slot*64 + tid], t2);
  }
}

// GELU: tanh-form collapses to a * sigmoid(2k(a + 0.044715 a^3)), k=sqrt(2/pi).
// Max |diff| vs exact erf-GELU ~3e-4, far under the bf16 absmax slack.
static __device__ __forceinline__ float gelu1(float a){
  float u = a*a;
  float wv = fmaf(u*a, -0.0713548162726f, a * -1.5957691216f);  // -2k(a+c a^3)
  return a * __builtin_amdgcn_rcpf(1.f + __expf(wv));
}

// ---------------- K5: BN finalize (redundant per block) + apply + GELU ------
__global__ __launch_bounds__(256) void k_bn_gelu(
    const uint4* __restrict__ outB4,   // 8 bf16
    const float* __restrict__ gsumS,
    const float* __restrict__ gsqS,
    const float* __restrict__ gamma,
    const float* __restrict__ beta,
    float4* __restrict__ y4)
{
  int i = blockIdx.x*256 + threadIdx.x;           // over NELEM_/8
  int och = (i >> 13) & 63;                       // block-uniform
  float s1 = 0.f, s2 = 0.f;
#pragma unroll
  for (int s = 0; s < 32; ++s){ s1 += gsumS[s*64 + och]; s2 += gsqS[s*64 + och]; }
  float mean = s1 * (1.f/(float)NPIX_);
  float var  = s2 * (1.f/(float)NPIX_) - mean*mean;   // biased, matches jnp.var
  float sc = gamma[och] * rsqrtf(var + 1e-5f);
  float sh = beta[och] - mean*sc;

  uint4 u = outB4[i];
  float e[8];
  e[0] = bf2f((unsigned short)(u.x & 0xffffu)); e[1] = bf2f((unsigned short)(u.x >> 16));
  e[2] = bf2f((unsigned short)(u.y & 0xffffu)); e[3] = bf2f((unsigned short)(u.y >> 16));
  e[4] = bf2f((unsigned short)(u.z & 0xffffu)); e[5] = bf2f((unsigned short)(u.z >> 16));
  e[6] = bf2f((unsigned short)(u.w & 0xffffu)); e[7] = bf2f((unsigned short)(u.w >> 16));
  float4 o0, o1;
  o0.x = gelu1(fmaf(e[0], sc, sh));
  o0.y = gelu1(fmaf(e[1], sc, sh));
  o0.z = gelu1(fmaf(e[2], sc, sh));
  o0.w = gelu1(fmaf(e[3], sc, sh));
  o1.x = gelu1(fmaf(e[4], sc, sh));
  o1.y = gelu1(fmaf(e[5], sc, sh));
  o1.z = gelu1(fmaf(e[6], sc, sh));
  o1.w = gelu1(fmaf(e[7], sc, sh));
  y4[2*i]   = o0;
  y4[2*i+1] = o1;
}

extern "C" void kernel_launch(void* const* d_in, const int* in_sizes, int n_in,
                              void* d_out, int out_size, void* d_ws, size_t ws_size,
                              hipStream_t stream)
{
  (void)in_sizes; (void)n_in; (void)out_size; (void)ws_size;
  const float* x     = (const float*)d_in[0];
  const float* dw    = (const float*)d_in[1];
  const float* pw    = (const float*)d_in[2];
  const float* w2    = (const float*)d_in[3];
  /* d_in[4] = bias: cancels exactly in BN (mean-subtracted), unused */
  const float* gamma = (const float*)d_in[5];
  const float* beta  = (const float*)d_in[6];

  // ws layout:
  //   [0,          33554432)  xB    bf16 x
  //   [33554432,   67108864)  t     bf16 dwconv out [px][c]
  //   [67108864,  100663296)  outB  bf16 conv2 out, och-major
  //   [100663296, 100680192)  stats (gsumS 8K, gsqS 8K)
  //   [100680192, 100712960)  wB    bf16 weights (pw 24K, w2 8K)
  char* ws = (char*)d_ws;
  unsigned short* xB    = (unsigned short*)ws;
  unsigned short* t     = (unsigned short*)(ws + 33554432);
  unsigned short* outB  = (unsigned short*)(ws + 67108864);
  float*          stats = (float*)(ws + 100663296);
  float* gsumS = stats;                 // 32 slots x 64
  float* gsqS  = stats + 2048;
  unsigned short* wB  = (unsigned short*)(ws + 100680192);
  unsigned short* pwB = wB;
  unsigned short* w2B = wB + 12288;

  k_dwconv  <<<NPIX_/64, 256, 0, stream>>>(x, dw, pw, w2, wB, stats, xB, t);
  k_fuse    <<<NPIX_/64, 256, 0, stream>>>(xB, t, pwB, w2B, outB, gsumS, gsqS);
  k_bn_gelu <<<NELEM_/8/256, 256, 0, stream>>>((const uint4*)outB, gsumS, gsqS,
                                               gamma, beta, (float4*)d_out);
}

// Round 9
// 258.592 us; speedup vs baseline: 1.1852x; 1.1537x over previous
//
#include <hip/hip_runtime.h>

#define B_  4
#define C_  64
#define H_  256
#define W_  256
#define HW_ 65536
#define NPIX_ (B_*HW_)        /* 262144 */
#define NELEM_ (B_*C_*HW_)    /* 16777216 */

#define OMS 200     /* bf16 om row stride in LDS (400B: 16B-aligned) */
#define TS  72      /* bf16 t/sval row stride in LDS (144B: 16B-aligned) */

typedef __attribute__((ext_vector_type(8))) short short8;
typedef __attribute__((ext_vector_type(4))) float floatx4;
typedef __attribute__((ext_vector_type(2))) __fp16 h2f;   // matches cvt_pkrtz return

static __device__ __forceinline__ unsigned short f2bf(float f){
  unsigned u = __float_as_uint(f);
  u += 0x7fff + ((u >> 16) & 1);          // RNE
  return (unsigned short)(u >> 16);
}
static __device__ __forceinline__ float bf2f(unsigned short s){
  return __uint_as_float(((unsigned)s) << 16);
}
static __device__ __forceinline__ unsigned pack2(float a, float b){
  return (unsigned)f2bf(a) | ((unsigned)f2bf(b) << 16);
}

// ---------------- K0: weights -> bf16, zero stats ---------------------------
__global__ __launch_bounds__(256) void k_setup(
    const float* __restrict__ pw, const float* __restrict__ w2,
    unsigned short* __restrict__ wB, float* __restrict__ stats0)
{
  int tid = threadIdx.x;
  if (blockIdx.x < 64){
    int i = blockIdx.x*256 + tid;
    wB[i] = f2bf(i < 12288 ? pw[i] : w2[i - 12288]);
  } else {
#pragma unroll
    for (int k = 0; k < 16; ++k) stats0[k*256 + tid] = 0.f;
  }
}

// ---------------- K1: MEGA-FUSED dwconv -> GEMM1 -> sample -> GEMM2 ---------
// The block's 64 pixels are one image-row chunk; dwconv for exactly these
// pixels runs as an in-kernel prologue writing t to LDS (never to HBM).
// Phase B gathers fp32 directly from x (input, always available; float2
// pair loads) -- xB and t intermediate buffers are eliminated entirely.
__global__ __launch_bounds__(256, 4) void k_fuse(
    const float* __restrict__ x,
    const float* __restrict__ dwW,
    const unsigned short* __restrict__ pwB,
    const unsigned short* __restrict__ w2B,
    unsigned short* __restrict__ outB,
    float* __restrict__ gsumS,
    float* __restrict__ gsqS)
{
  __shared__ __align__(16) char lds[34816];
  unsigned short* T  = (unsigned short*)lds;            // 64 x TS bf16: t, then sampled
  unsigned short* OM = (unsigned short*)(lds + 9216);   // 64 x OMS bf16 (25600 B)
  float* red1 = (float*)(lds + 9216);                   // overlays OM (dead by phase C)
  float* red2 = (float*)(lds + 10240);

  int tid = threadIdx.x;
  int bid = ((blockIdx.x & 7) << 9) + (blockIdx.x >> 3);   // XCD-contiguous
  int b    = bid >> 10;
  int tile = bid & 1023;
  int h    = tile >> 2;
  int w0   = (tile & 3) << 6;
  int p  = tid & 63;            // block-local pixel (column)
  int cg = tid >> 6;            // channel group (wave-uniform)
  int wg = w0 + p;

  // ======== phase 0: dwconv 3x3 (fp32 x) -> t bf16 in LDS ========
  {
    int rm = (h > 0   ? h-1 : 0) << 8;
    int r0 = h << 8;
    int rp = (h < 255 ? h+1 : 255) << 8;
    float vm = (h > 0)   ? 1.f : 0.f;
    float vp = (h < 255) ? 1.f : 0.f;
    int st = min(max(wg - 1, 0), 253);
    int d  = wg - st;                      // 0: wg==0, 2: wg==255, else 1
    bool d0 = (d == 0), d2 = (d == 2);
    int om = (rm + st) << 2;
    int oc = (r0 + st) << 2;
    int op = (rp + st) << 2;

    const char* plane0 = (const char*)(x + ((size_t)(b*C_ + cg*16) << 16));

    unsigned pk[8];
#pragma unroll
    for (int ib = 0; ib < 4; ++ib){       // 4 batches of 4 channels
      float3 v[4][3];
#pragma unroll
      for (int j = 0; j < 4; ++j){
        const char* pl = plane0 + (((size_t)(ib*4 + j)) << 18);
        __builtin_memcpy(&v[j][0], pl + om, 12);
        __builtin_memcpy(&v[j][1], pl + oc, 12);
        __builtin_memcpy(&v[j][2], pl + op, 12);
      }
      __builtin_amdgcn_sched_barrier(0);   // loads may not sink past this
#pragma unroll
      for (int j = 0; j < 4; ++j){
        int i = ib*4 + j;
        int c = cg*16 + i;
        const float* wp = dwW + c*9;       // wave-uniform -> scalar loads
        float acc = 0.f;
#pragma unroll
        for (int r = 0; r < 3; ++r){
          float3 f = v[j][r];
          float xl = d0 ? 0.f : (d2 ? f.y : f.x);
          float xc = d0 ? f.x : (d2 ? f.z : f.y);
          float xr = d2 ? 0.f : (d0 ? f.y : f.z);
          float rowscale = (r == 0) ? vm : (r == 2 ? vp : 1.f);
          acc += rowscale * (wp[r*3+0]*xl + wp[r*3+1]*xc + wp[r*3+2]*xr);
        }
        unsigned short bv = f2bf(acc);
        if (i & 1) pk[i>>1] |= ((unsigned)bv << 16);
        else       pk[i>>1]  = (unsigned)bv;
      }
    }
    uint4 u0; u0.x = pk[0]; u0.y = pk[1]; u0.z = pk[2]; u0.w = pk[3];
    uint4 u1; u1.x = pk[4]; u1.y = pk[5]; u1.z = pk[6]; u1.w = pk[7];
    *(uint4*)(T + p*TS + cg*16)     = u0;
    *(uint4*)(T + p*TS + cg*16 + 8) = u1;
  }
  __syncthreads();

  int wv = tid >> 6, lane = tid & 63;
  int mrow = lane & 15, q = lane >> 4;
  int pxw = bid*64 + wv*16;     // wave's pixel base (16 px per wave)

  // ======== phase A: GEMM1  om[px][ch] = sum_c t[px][c]*pw[ch][c] ========
  short8 bfrag[2];
#pragma unroll
  for (int kb = 0; kb < 2; ++kb)
    bfrag[kb] = *(const short8*)(T + (wv*16 + mrow)*TS + kb*32 + q*8);

  floatx4 acc[12];
#pragma unroll
  for (int mt = 0; mt < 12; ++mt) acc[mt] = (floatx4){0.f,0.f,0.f,0.f};
#pragma unroll
  for (int kb = 0; kb < 2; ++kb)
#pragma unroll
    for (int mt = 0; mt < 12; ++mt){
      short8 af = *(const short8*)(pwB + (mt*16 + mrow)*64 + kb*32 + q*8);
      acc[mt] = __builtin_amdgcn_mfma_f32_16x16x32_bf16(af, bfrag[kb], acc[mt], 0, 0, 0);
    }

  {
    int omrow = (wv*16 + mrow)*OMS;
#pragma unroll
    for (int mt = 0; mt < 12; ++mt){
      uint2 u; u.x = pack2(acc[mt][0], acc[mt][1]); u.y = pack2(acc[mt][2], acc[mt][3]);
      *(uint2*)(OM + omrow + mt*16 + q*4) = u;
    }
  }
  __syncthreads();

  // ======== phase B: deformable bilinear sampling, fp32 gathers from x =====
  unsigned pk[8];
  {
    float hf = (float)h, wf = (float)(w0 + p);   // this thread's pixel
    const char* xbyte = (const char*)(x + ((size_t)(b*C_ + cg*16) << 16));

#pragma unroll
    for (int half = 0; half < 2; ++half){
      const uint4* ob = (const uint4*)(OM + p*OMS + cg*32 + half*16);
      uint4 oA = ob[0], oB = ob[1];
      uint4 mv = *(const uint4*)(OM + p*OMS + 128 + cg*16 + half*8);
      unsigned pr[8] = {oA.x,oA.y,oA.z,oA.w, oB.x,oB.y,oB.z,oB.w};
      unsigned md4[4] = {mv.x,mv.y,mv.z,mv.w};

      h2f wrv[8], wcv[8];
      unsigned ad0[8], ad1[8];

      // ---- stage: weights + addresses ----
#pragma unroll
      for (int i = 0; i < 8; ++i){
        unsigned pair = pr[i];
        float oy = __uint_as_float(pair << 16);
        float ox = __uint_as_float(pair & 0xffff0000u);
        float mm = __uint_as_float((i & 1) ? (md4[i>>1] & 0xffff0000u)
                                           : (md4[i>>1] << 16));
        float mod = 2.f * __builtin_amdgcn_rcpf(1.f + __expf(-mm));
        oy = fminf(fmaxf(oy, -64.f), 64.f);
        ox = fminf(fmaxf(ox, -64.f), 64.f);
        float sy = hf + oy, sx = wf + ox;
        float y0f = floorf(sy), x0f = floorf(sx);
        float wy = sy - y0f, wxr = sx - x0f;
        int y0 = (int)y0f, x0 = (int)x0f;
        int yc0 = min(max(y0,     0), 255);
        int yc1 = min(max(y0 + 1, 0), 255);    // clamp AFTER increment
        int xc  = min(max(x0, 0), 254);        // pair start (always in-plane)
        bool y0v = ((unsigned)y0       < 256u);
        bool y1v = ((unsigned)(y0 + 1) < 256u);
        bool x0v = ((unsigned)x0       < 256u);
        bool x1v = ((unsigned)(x0 + 1) < 256u);
        bool x0lo = (x0 == xc);
        float r0 = y0v ? (1.f - wy) * mod : 0.f;
        float r1 = y1v ? wy * mod : 0.f;
        float c0w = x0v ? (1.f - wxr) : 0.f;
        float c1w = x1v ? wxr : 0.f;
        float cA = x0lo ? c0w : c1w;           // weight on value at xc
        float cB = x0lo ? c1w : c0w;           // weight on value at xc+1
        wrv[i] = __builtin_amdgcn_cvt_pkrtz(r0, r1);
        wcv[i] = __builtin_amdgcn_cvt_pkrtz(cA, cB);
        unsigned cb = ((unsigned)(half*8 + i)) << 18;   // fp32 plane = 256 KB
        ad0[i] = cb + ((unsigned)yc0 << 10) + ((unsigned)xc << 2);
        ad1[i] = cb + ((unsigned)yc1 << 10) + ((unsigned)xc << 2);
      }

      // ---- issue all 16 8-byte gathers ----
      float2 pu0[8], pu1[8];
#pragma unroll
      for (int i = 0; i < 8; ++i){
        __builtin_memcpy(&pu0[i], xbyte + ad0[i], 8);   // (y0 , x: xc, xc+1)
        __builtin_memcpy(&pu1[i], xbyte + ad1[i], 8);   // (y0+1, same)
      }
      __builtin_amdgcn_sched_barrier(0);   // loads may not sink below here

      // ---- consume ----
#pragma unroll
      for (int i = 0; i < 8; ++i){
        int ci = half*8 + i;
        float cA = (float)wcv[i].x, cB = (float)wcv[i].y;
        float r0 = (float)wrv[i].x, r1 = (float)wrv[i].y;
        float sres = r0*(cA*pu0[i].x + cB*pu0[i].y)
                   + r1*(cA*pu1[i].x + cB*pu1[i].y);
        unsigned short bv = f2bf(sres);
        if (ci & 1) pk[ci>>1] |= ((unsigned)bv << 16);
        else        pk[ci>>1]  = (unsigned)bv;
      }
    }
  }
  __syncthreads();              // all OM+t reads done; T may be overwritten

  {
    uint4 u0; u0.x = pk[0]; u0.y = pk[1]; u0.z = pk[2]; u0.w = pk[3];
    uint4 u1; u1.x = pk[4]; u1.y = pk[5]; u1.z = pk[6]; u1.w = pk[7];
    *(uint4*)(T + p*TS + cg*16)     = u0;
    *(uint4*)(T + p*TS + cg*16 + 8) = u1;
  }
  __syncthreads();

  // ======== phase C: GEMM2  out[px][och] = sum_c sval[px][c]*w2[och][c] ====
  short8 a2[2];
#pragma unroll
  for (int kb = 0; kb < 2; ++kb)
    a2[kb] = *(const short8*)(T + (wv*16 + mrow)*TS + kb*32 + q*8);

  floatx4 acc2[4];
#pragma unroll
  for (int nt = 0; nt < 4; ++nt) acc2[nt] = (floatx4){0.f,0.f,0.f,0.f};
#pragma unroll
  for (int kb = 0; kb < 2; ++kb)
#pragma unroll
    for (int nt = 0; nt < 4; ++nt){
      short8 bf = *(const short8*)(w2B + (nt*16 + mrow)*64 + kb*32 + q*8);
      acc2[nt] = __builtin_amdgcn_mfma_f32_16x16x32_bf16(a2[kb], bf, acc2[nt], 0, 0, 0);
    }

  int bb  = pxw >> 16;
  int hw0 = pxw & (HW_-1);
#pragma unroll
  for (int nt = 0; nt < 4; ++nt){
    int och = nt*16 + mrow;
    float a0 = acc2[nt][0], a1 = acc2[nt][1], a2v = acc2[nt][2], a3 = acc2[nt][3];
    uint2 u; u.x = pack2(a0, a1); u.y = pack2(a2v, a3);
    *(uint2*)(outB + ((size_t)(bb*C_ + och) << 16) + hw0 + q*4) = u;
    float s1 = a0 + a1 + a2v + a3;
    float s2 = a0*a0 + a1*a1 + a2v*a2v + a3*a3;
    s1 += __shfl_xor(s1, 16, 64);  s2 += __shfl_xor(s2, 16, 64);
    s1 += __shfl_xor(s1, 32, 64);  s2 += __shfl_xor(s2, 32, 64);
    if (q == 0){ red1[wv*64 + och] = s1; red2[wv*64 + och] = s2; }
  }
  __syncthreads();
  if (tid < 64){
    float t1 = red1[tid] + red1[64+tid] + red1[128+tid] + red1[192+tid];
    float t2 = red2[tid] + red2[64+tid] + red2[128+tid] + red2[192+tid];
    int slot = blockIdx.x & 31;
    atomicAdd(&gsumS[slot*64 + tid], t1);
    atomicAdd(&gsqS[slot*64 + tid], t2);
  }
}

// GELU: tanh-form collapses to a * sigmoid(2k(a + 0.044715 a^3)), k=sqrt(2/pi).
static __device__ __forceinline__ float gelu1(float a){
  float u = a*a;
  float wv = fmaf(u*a, -0.0713548162726f, a * -1.5957691216f);  // -2k(a+c a^3)
  return a * __builtin_amdgcn_rcpf(1.f + __expf(wv));
}

// ---------------- K5: BN finalize (redundant per block) + apply + GELU ------
__global__ __launch_bounds__(256) void k_bn_gelu(
    const uint4* __restrict__ outB4,   // 8 bf16
    const float* __restrict__ gsumS,
    const float* __restrict__ gsqS,
    const float* __restrict__ gamma,
    const float* __restrict__ beta,
    float4* __restrict__ y4)
{
  int i = blockIdx.x*256 + threadIdx.x;           // over NELEM_/8
  int och = (i >> 13) & 63;                       // block-uniform
  float s1 = 0.f, s2 = 0.f;
#pragma unroll
  for (int s = 0; s < 32; ++s){ s1 += gsumS[s*64 + och]; s2 += gsqS[s*64 + och]; }
  float mean = s1 * (1.f/(float)NPIX_);
  float var  = s2 * (1.f/(float)NPIX_) - mean*mean;   // biased, matches jnp.var
  float sc = gamma[och] * rsqrtf(var + 1e-5f);
  float sh = beta[och] - mean*sc;

  uint4 u = outB4[i];
  float e[8];
  e[0] = bf2f((unsigned short)(u.x & 0xffffu)); e[1] = bf2f((unsigned short)(u.x >> 16));
  e[2] = bf2f((unsigned short)(u.y & 0xffffu)); e[3] = bf2f((unsigned short)(u.y >> 16));
  e[4] = bf2f((unsigned short)(u.z & 0xffffu)); e[5] = bf2f((unsigned short)(u.z >> 16));
  e[6] = bf2f((unsigned short)(u.w & 0xffffu)); e[7] = bf2f((unsigned short)(u.w >> 16));
  float4 o0, o1;
  o0.x = gelu1(fmaf(e[0], sc, sh));
  o0.y = gelu1(fmaf(e[1], sc, sh));
  o0.z = gelu1(fmaf(e[2], sc, sh));
  o0.w = gelu1(fmaf(e[3], sc, sh));
  o1.x = gelu1(fmaf(e[4], sc, sh));
  o1.y = gelu1(fmaf(e[5], sc, sh));
  o1.z = gelu1(fmaf(e[6], sc, sh));
  o1.w = gelu1(fmaf(e[7], sc, sh));
  y4[2*i]   = o0;
  y4[2*i+1] = o1;
}

extern "C" void kernel_launch(void* const* d_in, const int* in_sizes, int n_in,
                              void* d_out, int out_size, void* d_ws, size_t ws_size,
                              hipStream_t stream)
{
  (void)in_sizes; (void)n_in; (void)out_size; (void)ws_size;
  const float* x     = (const float*)d_in[0];
  const float* dw    = (const float*)d_in[1];
  const float* pw    = (const float*)d_in[2];
  const float* w2    = (const float*)d_in[3];
  /* d_in[4] = bias: cancels exactly in BN (mean-subtracted), unused */
  const float* gamma = (const float*)d_in[5];
  const float* beta  = (const float*)d_in[6];

  // ws layout (xB and t eliminated):
  //   [0,         33554432)  outB  bf16 conv2 out, och-major
  //   [33554432,  33570816)  stats (gsumS 8K, gsqS 8K)
  //   [33570816,  33603584)  wB    bf16 weights (pw 24K, w2 8K)
  char* ws = (char*)d_ws;
  unsigned short* outB  = (unsigned short*)ws;
  float*          stats = (float*)(ws + 33554432);
  float* gsumS = stats;                 // 32 slots x 64
  float* gsqS  = stats + 2048;
  unsigned short* wB  = (unsigned short*)(ws + 33570816);
  unsigned short* pwB = wB;
  unsigned short* w2B = wB + 12288;

  k_setup   <<<65, 256, 0, stream>>>(pw, w2, wB, stats);
  k_fuse    <<<NPIX_/64, 256, 0, stream>>>(x, dw, pwB, w2B, outB, gsumS, gsqS);
  k_bn_gelu <<<NELEM_/8/256, 256, 0, stream>>>((const uint4*)outB, gsumS, gsqS,
                                               gamma, beta, (float4*)d_out);
}